// Round 10
// baseline (443.759 us; speedup 1.0000x reference)
//
#include <hip/hip_runtime.h>
#include <cstdint>
#include <cstddef>

typedef __attribute__((ext_vector_type(4))) float  floatx4;
typedef __attribute__((ext_vector_type(8))) __bf16 bf16x8;
typedef __attribute__((ext_vector_type(4))) __bf16 bf16x4;

#define B_   2
#define T_   2048
#define D_   2048
#define H_   16
#define DK   128
#define BT_  (B_ * T_)    // 4096 rows
#define N3   (3 * D_)     // 6144

// async global->LDS, 16B per lane. LDS dest must be (wave-uniform base + lane*16).
__device__ __forceinline__ void async_copy16(const void* g, void* l) {
    __builtin_amdgcn_global_load_lds((const __attribute__((address_space(1))) void*)g,
                                     (__attribute__((address_space(3))) void*)l,
                                     16, 0, 0);
}

// ---------------------------------------------------------------------------
// prep kernels
// ---------------------------------------------------------------------------
__global__ void cast_bf16_kernel(const float* __restrict__ in, __bf16* __restrict__ out, int n4) {
    int i = blockIdx.x * 256 + threadIdx.x;
    if (i >= n4) return;
    float4 v = ((const float4*)in)[i];
    bf16x4 o;
    o.x = (__bf16)v.x; o.y = (__bf16)v.y; o.z = (__bf16)v.z; o.w = (__bf16)v.w;
    ((bf16x4*)out)[i] = o;
}

// in [R][C] fp32 -> out [C][R] bf16, 64x64 tiles: float4 loads (16B/lane),
// LDS-padded transpose (<=2-way conflicts), bf16x8 stores (16B/lane).
__global__ __launch_bounds__(256)
void transcast_kernel(const float* __restrict__ in, __bf16* __restrict__ out, int R, int C) {
    __shared__ float tile[64][65];
    const int tid = threadIdx.x;
    const int r0 = blockIdx.y * 64, c0 = blockIdx.x * 64;
#pragma unroll
    for (int p = 0; p < 4; ++p) {
        int u = p * 256 + tid;
        int r = u >> 4, c4 = (u & 15) * 4;
        float4 v = *(const float4*)(in + (size_t)(r0 + r) * C + c0 + c4);
        tile[r][c4 + 0] = v.x; tile[r][c4 + 1] = v.y;
        tile[r][c4 + 2] = v.z; tile[r][c4 + 3] = v.w;
    }
    __syncthreads();
#pragma unroll
    for (int p = 0; p < 2; ++p) {
        int v = p * 256 + tid;
        int cc = v >> 3, rr = (v & 7) * 8;
        bf16x8 o;
#pragma unroll
        for (int i2 = 0; i2 < 8; ++i2) o[i2] = (__bf16)tile[rr + i2][cc];
        *(bf16x8*)(out + (size_t)(c0 + cc) * R + r0 + rr) = o;
    }
}

// ---------------------------------------------------------------------------
// m97-style GEMM, BK=64 (proven 132us/781TF structure): C = A * BT^T + bias.
// Plain linear block mapping -- MEASURED best (R5 vs R7/R8: both XCD swizzle
// variants inflated FETCH 3x, 107 -> 315-335 MB, and ran slower).
// ---------------------------------------------------------------------------
template <typename OutT>
__global__ __launch_bounds__(256)
void gemm_bt(const __bf16* __restrict__ A, const __bf16* __restrict__ BTm,
             const float* __restrict__ bias, OutT* __restrict__ C,
             int M, int N, int K) {
    __shared__ __align__(16) __bf16 As[128 * 64];
    __shared__ __align__(16) __bf16 Bs[128 * 64];
    const int tid  = threadIdx.x;
    const int lane = tid & 63;
    const int wave = tid >> 6;
    const int quad = lane >> 4;
    const int l16  = lane & 15;
    const int m0 = blockIdx.y * 128;
    const int n0 = blockIdx.x * 128;
    const int wm = (wave & 1) * 64;
    const int wn = (wave >> 1) * 64;

    const floatx4 z4 = {0.f, 0.f, 0.f, 0.f};
    floatx4 acc[4][4];
#pragma unroll
    for (int i = 0; i < 4; ++i)
#pragma unroll
        for (int j = 0; j < 4; ++j) acc[i][j] = z4;

    int           sOff[4];
    const __bf16* gA[4];
    const __bf16* gB[4];
#pragma unroll
    for (int i = 0; i < 4; ++i) {
        int s = i * 256 + tid;
        int row = s >> 3, cs = s & 7;
        int gc = cs ^ (row & 7);
        sOff[i] = s * 8;
        gA[i] = A   + (size_t)(m0 + row) * K + gc * 8;
        gB[i] = BTm + (size_t)(n0 + row) * K + gc * 8;
    }

    for (int kt = 0; kt < K; kt += 64) {
        __syncthreads();
#pragma unroll
        for (int i = 0; i < 4; ++i) {
            async_copy16(gA[i] + kt, As + sOff[i]);
            async_copy16(gB[i] + kt, Bs + sOff[i]);
        }
        __syncthreads();
#pragma unroll
        for (int ks2 = 0; ks2 < 2; ++ks2) {
            bf16x8 af[4], bf[4];
#pragma unroll
            for (int t = 0; t < 4; ++t) {
                int rowA = wm + t * 16 + l16;
                int ca = (ks2 * 4 + quad) ^ (rowA & 7);
                af[t] = *(const bf16x8*)(As + rowA * 64 + ca * 8);
                int rowB = wn + t * 16 + l16;
                int cb = (ks2 * 4 + quad) ^ (rowB & 7);
                bf[t] = *(const bf16x8*)(Bs + rowB * 64 + cb * 8);
            }
#pragma unroll
            for (int mt = 0; mt < 4; ++mt)
#pragma unroll
                for (int nt = 0; nt < 4; ++nt)
                    acc[mt][nt] = __builtin_amdgcn_mfma_f32_16x16x32_bf16(af[mt], bf[nt], acc[mt][nt], 0, 0, 0);
        }
    }

#pragma unroll
    for (int nt = 0; nt < 4; ++nt) {
        int n = n0 + wn + nt * 16 + l16;
        float bv = bias[n];
#pragma unroll
        for (int mt = 0; mt < 4; ++mt)
#pragma unroll
            for (int r = 0; r < 4; ++r) {
                int m = m0 + wm + mt * 16 + quad * 4 + r;
                C[(size_t)m * N + n] = (OutT)(acc[mt][nt][r] + bv);
            }
    }
}

// ---------------------------------------------------------------------------
// GEMM1 with FUSED rope + head-split + V-transpose epilogue (verified R5:
// 142us, FETCH 107MB, WRITE 58MB). Plain linear block mapping (see gemm_bt).
// ---------------------------------------------------------------------------
__global__ __launch_bounds__(256)
void gemm_kqv(const __bf16* __restrict__ A, const __bf16* __restrict__ BTm,
              const float* __restrict__ bias,
              __bf16* __restrict__ Kh, __bf16* __restrict__ Qh,
              __bf16* __restrict__ VT,
              int M, int N, int K) {
    __shared__ __align__(16) __bf16 smem[128 * 136];   // 34 KB: As|Bs, then V-transpose
    __bf16* As = smem;
    __bf16* Bs = smem + 128 * 64;
    const int tid  = threadIdx.x;
    const int lane = tid & 63;
    const int wave = tid >> 6;
    const int quad = lane >> 4;
    const int l16  = lane & 15;
    const int m0 = blockIdx.y * 128;
    const int n0 = blockIdx.x * 128;
    const int wm = (wave & 1) * 64;
    const int wn = (wave >> 1) * 64;

    const floatx4 z4 = {0.f, 0.f, 0.f, 0.f};
    floatx4 acc[4][4];
#pragma unroll
    for (int i = 0; i < 4; ++i)
#pragma unroll
        for (int j = 0; j < 4; ++j) acc[i][j] = z4;

    int           sOff[4];
    const __bf16* gA[4];
    const __bf16* gB[4];
#pragma unroll
    for (int i = 0; i < 4; ++i) {
        int s = i * 256 + tid;
        int row = s >> 3, cs = s & 7;
        int gc = cs ^ (row & 7);
        sOff[i] = s * 8;
        gA[i] = A   + (size_t)(m0 + row) * K + gc * 8;
        gB[i] = BTm + (size_t)(n0 + row) * K + gc * 8;
    }

    for (int kt = 0; kt < K; kt += 64) {
        __syncthreads();
#pragma unroll
        for (int i = 0; i < 4; ++i) {
            async_copy16(gA[i] + kt, As + sOff[i]);
            async_copy16(gB[i] + kt, Bs + sOff[i]);
        }
        __syncthreads();
#pragma unroll
        for (int ks2 = 0; ks2 < 2; ++ks2) {
            bf16x8 af[4], bf[4];
#pragma unroll
            for (int t = 0; t < 4; ++t) {
                int rowA = wm + t * 16 + l16;
                int ca = (ks2 * 4 + quad) ^ (rowA & 7);
                af[t] = *(const bf16x8*)(As + rowA * 64 + ca * 8);
                int rowB = wn + t * 16 + l16;
                int cb = (ks2 * 4 + quad) ^ (rowB & 7);
                bf[t] = *(const bf16x8*)(Bs + rowB * 64 + cb * 8);
            }
#pragma unroll
            for (int mt = 0; mt < 4; ++mt)
#pragma unroll
                for (int nt = 0; nt < 4; ++nt)
                    acc[mt][nt] = __builtin_amdgcn_mfma_f32_16x16x32_bf16(af[mt], bf[nt], acc[mt][nt], 0, 0, 0);
        }
    }

    // ---- fused epilogue ----
    const int which = n0 >> 11;               // 0=k,1=q,2=v (block-uniform)
    const int h  = (n0 & (D_ - 1)) >> 7;
    const int b  = m0 >> 11;
    const int t0 = m0 & (T_ - 1);
    const int bh = b * H_ + h;

    if (which == 2) {
        // V: transpose through LDS, then coalesced 16B-per-lane row stores
        __syncthreads();                      // main-loop LDS reads complete
#pragma unroll
        for (int nt = 0; nt < 4; ++nt) {
            const int n  = n0 + wn + nt * 16 + l16;
            const float bv = bias[n];
            const int dd = wn + nt * 16 + l16;
#pragma unroll
            for (int mt = 0; mt < 4; ++mt)
#pragma unroll
                for (int r = 0; r < 4; ++r) {
                    const int tl = wm + mt * 16 + quad * 4 + r;
                    smem[dd * 136 + tl] = (__bf16)(acc[mt][nt][r] + bv);
                }
        }
        __syncthreads();
#pragma unroll
        for (int i = 0; i < 8; ++i) {
            int s = i * 256 + tid;
            int dd = s >> 4, c = s & 15;
            bf16x8 vv = *(const bf16x8*)(smem + dd * 136 + c * 8);
            *(bf16x8*)(VT + ((size_t)bh * DK + dd) * T_ + t0 + c * 8) = vv;
        }
    } else {
        const float qscale = which ? 0.12751740f : 1.0f;  // log2e/sqrt(128)
        __bf16* dst = which ? Qh : Kh;
#pragma unroll
        for (int nt = 0; nt < 4; ++nt) {
            const int n  = n0 + wn + nt * 16 + l16;
            const float bv = bias[n];
            const int dd = wn + nt * 16 + l16;
            // rope freq (revolutions per t): 10000^(-(dd>>1)/64) / (2pi)
            const float freq_rev = 0.15915494309189535f *
                exp2f((float)(dd >> 1) * (-13.287712379549449f / 64.f));
#pragma unroll
            for (int mt = 0; mt < 4; ++mt)
#pragma unroll
                for (int r = 0; r < 4; ++r) {
                    const int t = t0 + wm + mt * 16 + quad * 4 + r;
                    const float val = acc[mt][nt][r] + bv;
                    const float other = __shfl_xor(val, 1);
                    const float x1 = (dd & 1) ? other : val;   // even-col value
                    const float x2 = (dd & 1) ? val : other;   // odd-col value
                    float rev = (float)t * freq_rev;
                    rev -= floorf(rev);
                    const float ang = rev * 6.283185307179586f;
                    const float sn = __sinf(ang), cn = __cosf(ang);
                    const float res = (dd & 1) ? (x1 * sn + x2 * cn)
                                               : (x1 * cn - x2 * sn);
                    dst[((size_t)bh * T_ + t) * DK + dd] = (__bf16)(res * qscale);
                }
        }
    }
}

// ---------------------------------------------------------------------------
// flash attention -- byte-identical to R8/R9 (swapped-operand, 8-wave
// QBLK=128, 4-deep K/V ring, 1 barrier/strip, counted vmcnt, defer-max,
// grid (bh=32, j=8)). FROZEN: this round measures it via duplicate launch.
// ---------------------------------------------------------------------------
__global__ __launch_bounds__(512)
void fa_kernel(const __bf16* __restrict__ Qg, const __bf16* __restrict__ Kg,
               const __bf16* __restrict__ VTg, __bf16* __restrict__ Og) {
    __shared__ __align__(16) __bf16 Ks[4][64 * 128];   // 64KB ring (Q stages in 0..1)
    __shared__ __align__(16) __bf16 Vs[4][128 * 64];   // 64KB ring
    __shared__ __align__(16) __bf16 Ps[8][16 * 64];    // 16KB (per-wave 2KB)
    const int tid  = threadIdx.x;
    const int lane = tid & 63, wave = tid >> 6;        // wave 0..7
    const int quad = lane >> 4, l16 = lane & 15;
    const int bh = blockIdx.x;          // 0..31  (XCD = bh%8)
    const int j  = blockIdx.y;          // 0..7
    const int b = bh >> 4, h = bh & 15;

    const __bf16* Kb = Kg  + (size_t)bh * T_ * DK;
    const __bf16* Vb = VTg + (size_t)bh * DK * T_;
    __bf16* Psw = Ps[wave];
    const int swzP = (l16 & 7) << 1;    // even XOR mask on 4-elem (8B) groups

    const floatx4 z4 = {0.f, 0.f, 0.f, 0.f};

    // staging addresses: 2 slots/thread/matrix (1024 slots x 16B = 16KB tile)
    int           sK[2], sV[2];
    const __bf16* gK[2];
    const __bf16* gV[2];
#pragma unroll
    for (int i = 0; i < 2; ++i) {
        int s = i * 512 + tid;
        { int row = s >> 4, cs = s & 15; int gc = cs ^ (row & 7);   // K: 128-elem rows
          sK[i] = s * 8; gK[i] = Kb + (size_t)row * DK + gc * 8; }
        { int row = s >> 3, cs = s & 7;  int gc = cs ^ (row & 7);   // V: 64-elem rows
          sV[i] = s * 8; gV[i] = Vb + (size_t)row * T_ + gc * 8; }
    }

    for (int half = 0; half < 2; ++half) {
        const int qt = half ? (15 - j) : j;      // 128-row Q tile index
        const int q0 = qt * 128;
        const int qpos = q0 + wave * 16 + l16;   // this lane's q-row
        const int nkt = 2 * qt + 2;              // 64-row K tiles (>= 2)

        // ---- prologue: stage Q tile (32KB) across Ks[0..1], lift to regs ----
        __syncthreads();   // full drain: previous half's compute + stores
        {
            const __bf16* Qb = Qg + (size_t)(bh * T_ + q0) * DK;
#pragma unroll
            for (int i = 0; i < 4; ++i) {
                int s = i * 512 + tid;           // 2048 slots: rows 0..127
                int row = s >> 4, cs = s & 15;
                int gc = cs ^ (row & 7);
                async_copy16(Qb + row * DK + gc * 8, &Ks[0][0] + s * 8);
            }
        }
        __syncthreads();   // vmcnt(0): Q staged
        bf16x8 qf[4];
#pragma unroll
        for (int ks = 0; ks < 4; ++ks) {
            int row = wave * 16 + l16;           // 0..127 spans Ks[0..1]
            int c = (ks * 4 + quad) ^ (row & 7);
            qf[ks] = *(const bf16x8*)(&Ks[0][0] + row * DK + c * 8);
        }
        __syncthreads();   // lgkmcnt(0): qf lifted before Ks overwrite

        // prologue prefetch: tiles 0,1 -> slots 0,1
#pragma unroll
        for (int tl = 0; tl < 2; ++tl) {
            const size_t koff = (size_t)tl * 64 * DK;
            const size_t voff = (size_t)tl * 64;
#pragma unroll
            for (int i = 0; i < 2; ++i) async_copy16(gK[i] + koff, &Ks[tl][0] + sK[i]);
#pragma unroll
            for (int i = 0; i < 2; ++i) async_copy16(gV[i] + voff, &Vs[tl][0] + sV[i]);
        }

        float m_i = -1e30f, l_i = 0.f;
        floatx4 accO[8];   // O^T tiles: accO[dt] -> d = dt*16+quad*4+r, q = l16
#pragma unroll
        for (int dt = 0; dt < 8; ++dt) accO[dt] = z4;

        for (int kt = 0; kt < nkt; ++kt) {
            // issue tile kt+2 into ring slot (kt+2)&3 (no WAR vs {kt-1,kt,kt+1})
            if (kt + 2 < nkt) {
                const int sl = (kt + 2) & 3;
                const size_t koff = (size_t)(kt + 2) * 64 * DK;
                const size_t voff = (size_t)(kt + 2) * 64;
#pragma unroll
                for (int i = 0; i < 2; ++i) async_copy16(gK[i] + koff, &Ks[sl][0] + sK[i]);
#pragma unroll
                for (int i = 0; i < 2; ++i) async_copy16(gV[i] + voff, &Vs[sl][0] + sV[i]);
            }
            const int rem = nkt - 1 - kt;        // tiles still in flight past kt
            if (rem >= 2)      asm volatile("s_waitcnt vmcnt(8)" ::: "memory");
            else if (rem == 1) asm volatile("s_waitcnt vmcnt(4)" ::: "memory");
            else               asm volatile("s_waitcnt vmcnt(0)" ::: "memory");
            __builtin_amdgcn_s_barrier();        // tile kt resident, strip kt-1 done

            const int cur = kt & 3;
            const __bf16* Kcur = &Ks[cur][0];
            const __bf16* Vcur = &Vs[cur][0];

            // S^T strip: sc[nt] covers k = kt*64+nt*16+quad*4+r, q = l16
            floatx4 sc[4];
#pragma unroll
            for (int nt = 0; nt < 4; ++nt) sc[nt] = z4;
            __builtin_amdgcn_s_setprio(1);
#pragma unroll
            for (int ks = 0; ks < 4; ++ks)
#pragma unroll
                for (int nt = 0; nt < 4; ++nt) {
                    int row = nt * 16 + l16;
                    int c = (ks * 4 + quad) ^ (row & 7);
                    bf16x8 kf = *(const bf16x8*)(Kcur + row * DK + c * 8);
                    sc[nt] = __builtin_amdgcn_mfma_f32_16x16x32_bf16(kf, qf[ks], sc[nt], 0, 0, 0);
                }
            __builtin_amdgcn_s_setprio(0);

            // causal mask (diagonal tiles only) + in-lane max
            float mnew = -1e30f;
            if (kt >= 2 * qt) {
#pragma unroll
                for (int nt = 0; nt < 4; ++nt) {
                    int kbase = kt * 64 + nt * 16 + quad * 4;
#pragma unroll
                    for (int r = 0; r < 4; ++r) {
                        float v = sc[nt][r];
                        v = (kbase + r > qpos) ? -1e30f : v;
                        sc[nt][r] = v;
                        mnew = fmaxf(mnew, v);
                    }
                }
            } else {
#pragma unroll
                for (int nt = 0; nt < 4; ++nt)
#pragma unroll
                    for (int r = 0; r < 4; ++r) mnew = fmaxf(mnew, sc[nt][r]);
            }
            // cross-quad reduce (q-row spread over lanes l16, +16, +32, +48)
            mnew = fmaxf(mnew, __shfl_xor(mnew, 16));
            mnew = fmaxf(mnew, __shfl_xor(mnew, 32));
            // T13 defer-max: rescale only if some lane's max grew by > 8
            if (!__all(mnew - m_i <= 8.0f)) {
                const float mi = fmaxf(m_i, mnew);
                const float alpha = exp2f(m_i - mi);   // base-2 softmax
                m_i = mi;
                l_i *= alpha;
#pragma unroll
                for (int dt = 0; dt < 8; ++dt)
#pragma unroll
                    for (int r = 0; r < 4; ++r) accO[dt][r] *= alpha;
            }

            float rs = 0.f;
#pragma unroll
            for (int nt = 0; nt < 4; ++nt)
#pragma unroll
                for (int r = 0; r < 4; ++r) {
                    float pv = exp2f(sc[nt][r] - m_i);   // bounded by 2^8
                    sc[nt][r] = pv;
                    rs += pv;
                }
            rs += __shfl_xor(rs, 16);
            rs += __shfl_xor(rs, 32);
            l_i += rs;

            // P^T -> LDS: row q=l16 (64 k's), 8B groups swizzled by g^=swzP
#pragma unroll
            for (int nt = 0; nt < 4; ++nt) {
                bf16x4 pw;
                pw.x = (__bf16)sc[nt][0]; pw.y = (__bf16)sc[nt][1];
                pw.z = (__bf16)sc[nt][2]; pw.w = (__bf16)sc[nt][3];
                int g = (nt * 4 + quad) ^ swzP;
                *(bf16x4*)(Psw + l16 * 64 + g * 4) = pw;
            }
            // O^T += V^T . P^T  (A = Vs rows, B = P^T frags from Psw)
            __builtin_amdgcn_s_setprio(1);
#pragma unroll
            for (int kc = 0; kc < 2; ++kc) {
                int gk = (kc * 8 + quad * 2) ^ swzP;   // even -> 16B aligned
                bf16x8 pb = *(const bf16x8*)(Psw + l16 * 64 + gk * 4);
#pragma unroll
                for (int dt = 0; dt < 8; ++dt) {
                    int vrow = dt * 16 + l16;
                    int vch = (kc * 4 + quad) ^ (vrow & 7);
                    bf16x8 vf = *(const bf16x8*)(Vcur + vrow * 64 + vch * 8);
                    accO[dt] = __builtin_amdgcn_mfma_f32_16x16x32_bf16(vf, pb, accO[dt], 0, 0, 0);
                }
            }
            __builtin_amdgcn_s_setprio(0);
            // no trailing barrier: ring slot (kt+3)&3 written next strip is
            // not read by any wave still inside strips kt or kt+1.
        }

        // ---- epilogue: accO is O^T; lane writes 8x 8B runs of its q-row ----
        const float inv = 1.0f / l_i;
        __bf16* orow = Og + (size_t)(b * T_ + qpos) * D_ + h * DK;
#pragma unroll
        for (int dt = 0; dt < 8; ++dt) {
            bf16x4 ow;
            ow.x = (__bf16)(accO[dt][0] * inv);
            ow.y = (__bf16)(accO[dt][1] * inv);
            ow.z = (__bf16)(accO[dt][2] * inv);
            ow.w = (__bf16)(accO[dt][3] * inv);
            *(bf16x4*)(orow + dt * 16 + quad * 4) = ow;
        }
    }
}

// ---------------------------------------------------------------------------
extern "C" void kernel_launch(void* const* d_in, const int* in_sizes, int n_in,
                              void* d_out, int out_size, void* d_ws, size_t ws_size,
                              hipStream_t stream) {
    const float* x    = (const float*)d_in[0];
    const float* Wkqv = (const float*)d_in[1];
    const float* bkqv = (const float*)d_in[2];
    const float* Wo   = (const float*)d_in[3];
    const float* bo   = (const float*)d_in[4];
    float* out = (float*)d_out;

    // workspace layout (128 MiB used of 160)
    char* p = (char*)d_ws;
    __bf16* xb    = (__bf16*)p; p += (size_t)BT_ * D_ * 2;  // 16 MiB
    __bf16* WkqvT = (__bf16*)p; p += (size_t)D_ * N3 * 2;   // 24 MiB
    __bf16* WoT   = (__bf16*)p; p += (size_t)D_ * D_ * 2;   //  8 MiB
    __bf16* qh    = (__bf16*)p; p += (size_t)BT_ * D_ * 2;  // 16 MiB
    __bf16* kh    = (__bf16*)p; p += (size_t)BT_ * D_ * 2;  // 16 MiB
    __bf16* vT    = (__bf16*)p; p += (size_t)BT_ * D_ * 2;  // 16 MiB
    __bf16* ao    = (__bf16*)p; p += (size_t)BT_ * D_ * 2;  // 16 MiB
    __bf16* ao2   = (__bf16*)p; p += (size_t)BT_ * D_ * 2;  // 16 MiB (scratch, measurement)

    cast_bf16_kernel<<<(BT_ * D_ / 4 + 255) / 256, 256, 0, stream>>>(x, xb, BT_ * D_ / 4);
    transcast_kernel<<<dim3(N3 / 64, D_ / 64), 256, 0, stream>>>(Wkqv, WkqvT, D_, N3);
    transcast_kernel<<<dim3(D_ / 64, D_ / 64), 256, 0, stream>>>(Wo, WoT, D_, D_);
    gemm_kqv<<<dim3(N3 / 128, BT_ / 128), 256, 0, stream>>>(xb, WkqvT, bkqv, kh, qh, vT, BT_, N3, D_);
    fa_kernel<<<dim3(B_ * H_, 8), 512, 0, stream>>>(qh, kh, vT, ao);
    gemm_bt<float><<<dim3(D_ / 128, BT_ / 128), 256, 0, stream>>>(ao, WoT, bo, out, BT_, D_, D_);
    // MEASUREMENT: duplicate fa launch into scratch; stream is serial, so
    // total_R10 - total_R9 == one fa_kernel duration (rocprof top-5 never
    // shows fa; this difference-measurement is the reliable alternative).
    fa_kernel<<<dim3(B_ * H_, 8), 512, 0, stream>>>(qh, kh, vT, ao2);
}

// Round 11
// 375.448 us; speedup vs baseline: 1.1819x; 1.1819x over previous
//
#include <hip/hip_runtime.h>
#include <cstdint>
#include <cstddef>

typedef __attribute__((ext_vector_type(4))) float  floatx4;
typedef __attribute__((ext_vector_type(8))) __bf16 bf16x8;
typedef __attribute__((ext_vector_type(4))) __bf16 bf16x4;

#define B_   2
#define T_   2048
#define D_   2048
#define H_   16
#define DK   128
#define BT_  (B_ * T_)    // 4096 rows
#define N3   (3 * D_)     // 6144

// async global->LDS, 16B per lane. LDS dest must be (wave-uniform base + lane*16).
__device__ __forceinline__ void async_copy16(const void* g, void* l) {
    __builtin_amdgcn_global_load_lds((const __attribute__((address_space(1))) void*)g,
                                     (__attribute__((address_space(3))) void*)l,
                                     16, 0, 0);
}

// ---------------------------------------------------------------------------
// FUSED prep kernel: one launch replaces cast_bf16 + transcast(Wkqv) +
// transcast(Wo). Bodies are byte-identical to the previously verified
// kernels; only the block-index decode changed. Branch is block-uniform.
//   blocks [0, 8192)        : x fp32 -> xb bf16 (float4/bf16x4 elementwise)
//   blocks [8192, 11264)    : Wkqv [2048][6144] -> WkqvT [6144][2048]
//   blocks [11264, 12288)   : Wo   [2048][2048] -> WoT   [2048][2048]
// ---------------------------------------------------------------------------
__device__ __forceinline__ void transcast_body(const float* __restrict__ in,
                                               __bf16* __restrict__ out,
                                               int R, int C, int r0, int c0,
                                               float (*tile)[65], int tid) {
#pragma unroll
    for (int p = 0; p < 4; ++p) {
        int u = p * 256 + tid;
        int r = u >> 4, c4 = (u & 15) * 4;
        float4 v = *(const float4*)(in + (size_t)(r0 + r) * C + c0 + c4);
        tile[r][c4 + 0] = v.x; tile[r][c4 + 1] = v.y;
        tile[r][c4 + 2] = v.z; tile[r][c4 + 3] = v.w;
    }
    __syncthreads();
#pragma unroll
    for (int p = 0; p < 2; ++p) {
        int v = p * 256 + tid;
        int cc = v >> 3, rr = (v & 7) * 8;
        bf16x8 o;
#pragma unroll
        for (int i2 = 0; i2 < 8; ++i2) o[i2] = (__bf16)tile[rr + i2][cc];
        *(bf16x8*)(out + (size_t)(c0 + cc) * R + r0 + rr) = o;
    }
}

__global__ __launch_bounds__(256)
void prep_kernel(const float* __restrict__ x, __bf16* __restrict__ xb,
                 const float* __restrict__ Wkqv, __bf16* __restrict__ WkqvT,
                 const float* __restrict__ Wo, __bf16* __restrict__ WoT) {
    __shared__ float tile[64][65];
    const int bid = blockIdx.x;
    const int tid = threadIdx.x;
    if (bid < 8192) {
        // x cast: 8192 blocks x 256 threads x 4 elems = BT_*D_ exactly
        int i = bid * 256 + tid;
        float4 v = ((const float4*)x)[i];
        bf16x4 o;
        o.x = (__bf16)v.x; o.y = (__bf16)v.y; o.z = (__bf16)v.z; o.w = (__bf16)v.w;
        ((bf16x4*)xb)[i] = o;
    } else if (bid < 8192 + 3072) {
        // Wkqv transcast: 96 x 32 tiles of 64x64
        int t = bid - 8192;
        transcast_body(Wkqv, WkqvT, D_, N3, (t / 96) * 64, (t % 96) * 64, tile, tid);
    } else {
        // Wo transcast: 32 x 32 tiles
        int t = bid - 11264;
        transcast_body(Wo, WoT, D_, D_, (t / 32) * 64, (t % 32) * 64, tile, tid);
    }
}

// ---------------------------------------------------------------------------
// m97-style GEMM, BK=64 (proven 132us/781TF structure): C = A * BT^T + bias.
// Plain linear block mapping -- MEASURED best (R5 vs R7/R8: both XCD swizzle
// variants inflated FETCH 3x, 107 -> 315-335 MB, and ran slower).
// ---------------------------------------------------------------------------
template <typename OutT>
__global__ __launch_bounds__(256)
void gemm_bt(const __bf16* __restrict__ A, const __bf16* __restrict__ BTm,
             const float* __restrict__ bias, OutT* __restrict__ C,
             int M, int N, int K) {
    __shared__ __align__(16) __bf16 As[128 * 64];
    __shared__ __align__(16) __bf16 Bs[128 * 64];
    const int tid  = threadIdx.x;
    const int lane = tid & 63;
    const int wave = tid >> 6;
    const int quad = lane >> 4;
    const int l16  = lane & 15;
    const int m0 = blockIdx.y * 128;
    const int n0 = blockIdx.x * 128;
    const int wm = (wave & 1) * 64;
    const int wn = (wave >> 1) * 64;

    const floatx4 z4 = {0.f, 0.f, 0.f, 0.f};
    floatx4 acc[4][4];
#pragma unroll
    for (int i = 0; i < 4; ++i)
#pragma unroll
        for (int j = 0; j < 4; ++j) acc[i][j] = z4;

    int           sOff[4];
    const __bf16* gA[4];
    const __bf16* gB[4];
#pragma unroll
    for (int i = 0; i < 4; ++i) {
        int s = i * 256 + tid;
        int row = s >> 3, cs = s & 7;
        int gc = cs ^ (row & 7);
        sOff[i] = s * 8;
        gA[i] = A   + (size_t)(m0 + row) * K + gc * 8;
        gB[i] = BTm + (size_t)(n0 + row) * K + gc * 8;
    }

    for (int kt = 0; kt < K; kt += 64) {
        __syncthreads();
#pragma unroll
        for (int i = 0; i < 4; ++i) {
            async_copy16(gA[i] + kt, As + sOff[i]);
            async_copy16(gB[i] + kt, Bs + sOff[i]);
        }
        __syncthreads();
#pragma unroll
        for (int ks2 = 0; ks2 < 2; ++ks2) {
            bf16x8 af[4], bf[4];
#pragma unroll
            for (int t = 0; t < 4; ++t) {
                int rowA = wm + t * 16 + l16;
                int ca = (ks2 * 4 + quad) ^ (rowA & 7);
                af[t] = *(const bf16x8*)(As + rowA * 64 + ca * 8);
                int rowB = wn + t * 16 + l16;
                int cb = (ks2 * 4 + quad) ^ (rowB & 7);
                bf[t] = *(const bf16x8*)(Bs + rowB * 64 + cb * 8);
            }
#pragma unroll
            for (int mt = 0; mt < 4; ++mt)
#pragma unroll
                for (int nt = 0; nt < 4; ++nt)
                    acc[mt][nt] = __builtin_amdgcn_mfma_f32_16x16x32_bf16(af[mt], bf[nt], acc[mt][nt], 0, 0, 0);
        }
    }

#pragma unroll
    for (int nt = 0; nt < 4; ++nt) {
        int n = n0 + wn + nt * 16 + l16;
        float bv = bias[n];
#pragma unroll
        for (int mt = 0; mt < 4; ++mt)
#pragma unroll
            for (int r = 0; r < 4; ++r) {
                int m = m0 + wm + mt * 16 + quad * 4 + r;
                C[(size_t)m * N + n] = (OutT)(acc[mt][nt][r] + bv);
            }
    }
}

// ---------------------------------------------------------------------------
// GEMM1 with FUSED rope + head-split + V-transpose epilogue (verified R5:
// 142us, FETCH 107MB, WRITE 58MB). Plain linear block mapping (see gemm_bt).
// ---------------------------------------------------------------------------
__global__ __launch_bounds__(256)
void gemm_kqv(const __bf16* __restrict__ A, const __bf16* __restrict__ BTm,
              const float* __restrict__ bias,
              __bf16* __restrict__ Kh, __bf16* __restrict__ Qh,
              __bf16* __restrict__ VT,
              int M, int N, int K) {
    __shared__ __align__(16) __bf16 smem[128 * 136];   // 34 KB: As|Bs, then V-transpose
    __bf16* As = smem;
    __bf16* Bs = smem + 128 * 64;
    const int tid  = threadIdx.x;
    const int lane = tid & 63;
    const int wave = tid >> 6;
    const int quad = lane >> 4;
    const int l16  = lane & 15;
    const int m0 = blockIdx.y * 128;
    const int n0 = blockIdx.x * 128;
    const int wm = (wave & 1) * 64;
    const int wn = (wave >> 1) * 64;

    const floatx4 z4 = {0.f, 0.f, 0.f, 0.f};
    floatx4 acc[4][4];
#pragma unroll
    for (int i = 0; i < 4; ++i)
#pragma unroll
        for (int j = 0; j < 4; ++j) acc[i][j] = z4;

    int           sOff[4];
    const __bf16* gA[4];
    const __bf16* gB[4];
#pragma unroll
    for (int i = 0; i < 4; ++i) {
        int s = i * 256 + tid;
        int row = s >> 3, cs = s & 7;
        int gc = cs ^ (row & 7);
        sOff[i] = s * 8;
        gA[i] = A   + (size_t)(m0 + row) * K + gc * 8;
        gB[i] = BTm + (size_t)(n0 + row) * K + gc * 8;
    }

    for (int kt = 0; kt < K; kt += 64) {
        __syncthreads();
#pragma unroll
        for (int i = 0; i < 4; ++i) {
            async_copy16(gA[i] + kt, As + sOff[i]);
            async_copy16(gB[i] + kt, Bs + sOff[i]);
        }
        __syncthreads();
#pragma unroll
        for (int ks2 = 0; ks2 < 2; ++ks2) {
            bf16x8 af[4], bf[4];
#pragma unroll
            for (int t = 0; t < 4; ++t) {
                int rowA = wm + t * 16 + l16;
                int ca = (ks2 * 4 + quad) ^ (rowA & 7);
                af[t] = *(const bf16x8*)(As + rowA * 64 + ca * 8);
                int rowB = wn + t * 16 + l16;
                int cb = (ks2 * 4 + quad) ^ (rowB & 7);
                bf[t] = *(const bf16x8*)(Bs + rowB * 64 + cb * 8);
            }
#pragma unroll
            for (int mt = 0; mt < 4; ++mt)
#pragma unroll
                for (int nt = 0; nt < 4; ++nt)
                    acc[mt][nt] = __builtin_amdgcn_mfma_f32_16x16x32_bf16(af[mt], bf[nt], acc[mt][nt], 0, 0, 0);
        }
    }

    // ---- fused epilogue ----
    const int which = n0 >> 11;               // 0=k,1=q,2=v (block-uniform)
    const int h  = (n0 & (D_ - 1)) >> 7;
    const int b  = m0 >> 11;
    const int t0 = m0 & (T_ - 1);
    const int bh = b * H_ + h;

    if (which == 2) {
        // V: transpose through LDS, then coalesced 16B-per-lane row stores
        __syncthreads();                      // main-loop LDS reads complete
#pragma unroll
        for (int nt = 0; nt < 4; ++nt) {
            const int n  = n0 + wn + nt * 16 + l16;
            const float bv = bias[n];
            const int dd = wn + nt * 16 + l16;
#pragma unroll
            for (int mt = 0; mt < 4; ++mt)
#pragma unroll
                for (int r = 0; r < 4; ++r) {
                    const int tl = wm + mt * 16 + quad * 4 + r;
                    smem[dd * 136 + tl] = (__bf16)(acc[mt][nt][r] + bv);
                }
        }
        __syncthreads();
#pragma unroll
        for (int i = 0; i < 8; ++i) {
            int s = i * 256 + tid;
            int dd = s >> 4, c = s & 15;
            bf16x8 vv = *(const bf16x8*)(smem + dd * 136 + c * 8);
            *(bf16x8*)(VT + ((size_t)bh * DK + dd) * T_ + t0 + c * 8) = vv;
        }
    } else {
        const float qscale = which ? 0.12751740f : 1.0f;  // log2e/sqrt(128)
        __bf16* dst = which ? Qh : Kh;
#pragma unroll
        for (int nt = 0; nt < 4; ++nt) {
            const int n  = n0 + wn + nt * 16 + l16;
            const float bv = bias[n];
            const int dd = wn + nt * 16 + l16;
            // rope freq (revolutions per t): 10000^(-(dd>>1)/64) / (2pi)
            const float freq_rev = 0.15915494309189535f *
                exp2f((float)(dd >> 1) * (-13.287712379549449f / 64.f));
#pragma unroll
            for (int mt = 0; mt < 4; ++mt)
#pragma unroll
                for (int r = 0; r < 4; ++r) {
                    const int t = t0 + wm + mt * 16 + quad * 4 + r;
                    const float val = acc[mt][nt][r] + bv;
                    const float other = __shfl_xor(val, 1);
                    const float x1 = (dd & 1) ? other : val;   // even-col value
                    const float x2 = (dd & 1) ? val : other;   // odd-col value
                    float rev = (float)t * freq_rev;
                    rev -= floorf(rev);
                    const float ang = rev * 6.283185307179586f;
                    const float sn = __sinf(ang), cn = __cosf(ang);
                    const float res = (dd & 1) ? (x1 * sn + x2 * cn)
                                               : (x1 * cn - x2 * sn);
                    dst[((size_t)bh * T_ + t) * DK + dd] = (__bf16)(res * qscale);
                }
        }
    }
}

// ---------------------------------------------------------------------------
// flash attention -- byte-identical to R8/R9/R10 (measured ~36-50us via the
// R10 duplicate-launch experiment; NOT the bottleneck). Swapped-operand,
// 8-wave QBLK=128, 4-deep K/V ring, 1 barrier/strip, counted vmcnt,
// defer-max, grid (bh=32, j=8).
// ---------------------------------------------------------------------------
__global__ __launch_bounds__(512)
void fa_kernel(const __bf16* __restrict__ Qg, const __bf16* __restrict__ Kg,
               const __bf16* __restrict__ VTg, __bf16* __restrict__ Og) {
    __shared__ __align__(16) __bf16 Ks[4][64 * 128];   // 64KB ring (Q stages in 0..1)
    __shared__ __align__(16) __bf16 Vs[4][128 * 64];   // 64KB ring
    __shared__ __align__(16) __bf16 Ps[8][16 * 64];    // 16KB (per-wave 2KB)
    const int tid  = threadIdx.x;
    const int lane = tid & 63, wave = tid >> 6;        // wave 0..7
    const int quad = lane >> 4, l16 = lane & 15;
    const int bh = blockIdx.x;          // 0..31  (XCD = bh%8)
    const int j  = blockIdx.y;          // 0..7
    const int b = bh >> 4, h = bh & 15;

    const __bf16* Kb = Kg  + (size_t)bh * T_ * DK;
    const __bf16* Vb = VTg + (size_t)bh * DK * T_;
    __bf16* Psw = Ps[wave];
    const int swzP = (l16 & 7) << 1;    // even XOR mask on 4-elem (8B) groups

    const floatx4 z4 = {0.f, 0.f, 0.f, 0.f};

    // staging addresses: 2 slots/thread/matrix (1024 slots x 16B = 16KB tile)
    int           sK[2], sV[2];
    const __bf16* gK[2];
    const __bf16* gV[2];
#pragma unroll
    for (int i = 0; i < 2; ++i) {
        int s = i * 512 + tid;
        { int row = s >> 4, cs = s & 15; int gc = cs ^ (row & 7);   // K: 128-elem rows
          sK[i] = s * 8; gK[i] = Kb + (size_t)row * DK + gc * 8; }
        { int row = s >> 3, cs = s & 7;  int gc = cs ^ (row & 7);   // V: 64-elem rows
          sV[i] = s * 8; gV[i] = Vb + (size_t)row * T_ + gc * 8; }
    }

    for (int half = 0; half < 2; ++half) {
        const int qt = half ? (15 - j) : j;      // 128-row Q tile index
        const int q0 = qt * 128;
        const int qpos = q0 + wave * 16 + l16;   // this lane's q-row
        const int nkt = 2 * qt + 2;              // 64-row K tiles (>= 2)

        // ---- prologue: stage Q tile (32KB) across Ks[0..1], lift to regs ----
        __syncthreads();   // full drain: previous half's compute + stores
        {
            const __bf16* Qb = Qg + (size_t)(bh * T_ + q0) * DK;
#pragma unroll
            for (int i = 0; i < 4; ++i) {
                int s = i * 512 + tid;           // 2048 slots: rows 0..127
                int row = s >> 4, cs = s & 15;
                int gc = cs ^ (row & 7);
                async_copy16(Qb + row * DK + gc * 8, &Ks[0][0] + s * 8);
            }
        }
        __syncthreads();   // vmcnt(0): Q staged
        bf16x8 qf[4];
#pragma unroll
        for (int ks = 0; ks < 4; ++ks) {
            int row = wave * 16 + l16;           // 0..127 spans Ks[0..1]
            int c = (ks * 4 + quad) ^ (row & 7);
            qf[ks] = *(const bf16x8*)(&Ks[0][0] + row * DK + c * 8);
        }
        __syncthreads();   // lgkmcnt(0): qf lifted before Ks overwrite

        // prologue prefetch: tiles 0,1 -> slots 0,1
#pragma unroll
        for (int tl = 0; tl < 2; ++tl) {
            const size_t koff = (size_t)tl * 64 * DK;
            const size_t voff = (size_t)tl * 64;
#pragma unroll
            for (int i = 0; i < 2; ++i) async_copy16(gK[i] + koff, &Ks[tl][0] + sK[i]);
#pragma unroll
            for (int i = 0; i < 2; ++i) async_copy16(gV[i] + voff, &Vs[tl][0] + sV[i]);
        }

        float m_i = -1e30f, l_i = 0.f;
        floatx4 accO[8];   // O^T tiles: accO[dt] -> d = dt*16+quad*4+r, q = l16
#pragma unroll
        for (int dt = 0; dt < 8; ++dt) accO[dt] = z4;

        for (int kt = 0; kt < nkt; ++kt) {
            // issue tile kt+2 into ring slot (kt+2)&3 (no WAR vs {kt-1,kt,kt+1})
            if (kt + 2 < nkt) {
                const int sl = (kt + 2) & 3;
                const size_t koff = (size_t)(kt + 2) * 64 * DK;
                const size_t voff = (size_t)(kt + 2) * 64;
#pragma unroll
                for (int i = 0; i < 2; ++i) async_copy16(gK[i] + koff, &Ks[sl][0] + sK[i]);
#pragma unroll
                for (int i = 0; i < 2; ++i) async_copy16(gV[i] + voff, &Vs[sl][0] + sV[i]);
            }
            const int rem = nkt - 1 - kt;        // tiles still in flight past kt
            if (rem >= 2)      asm volatile("s_waitcnt vmcnt(8)" ::: "memory");
            else if (rem == 1) asm volatile("s_waitcnt vmcnt(4)" ::: "memory");
            else               asm volatile("s_waitcnt vmcnt(0)" ::: "memory");
            __builtin_amdgcn_s_barrier();        // tile kt resident, strip kt-1 done

            const int cur = kt & 3;
            const __bf16* Kcur = &Ks[cur][0];
            const __bf16* Vcur = &Vs[cur][0];

            // S^T strip: sc[nt] covers k = kt*64+nt*16+quad*4+r, q = l16
            floatx4 sc[4];
#pragma unroll
            for (int nt = 0; nt < 4; ++nt) sc[nt] = z4;
            __builtin_amdgcn_s_setprio(1);
#pragma unroll
            for (int ks = 0; ks < 4; ++ks)
#pragma unroll
                for (int nt = 0; nt < 4; ++nt) {
                    int row = nt * 16 + l16;
                    int c = (ks * 4 + quad) ^ (row & 7);
                    bf16x8 kf = *(const bf16x8*)(Kcur + row * DK + c * 8);
                    sc[nt] = __builtin_amdgcn_mfma_f32_16x16x32_bf16(kf, qf[ks], sc[nt], 0, 0, 0);
                }
            __builtin_amdgcn_s_setprio(0);

            // causal mask (diagonal tiles only) + in-lane max
            float mnew = -1e30f;
            if (kt >= 2 * qt) {
#pragma unroll
                for (int nt = 0; nt < 4; ++nt) {
                    int kbase = kt * 64 + nt * 16 + quad * 4;
#pragma unroll
                    for (int r = 0; r < 4; ++r) {
                        float v = sc[nt][r];
                        v = (kbase + r > qpos) ? -1e30f : v;
                        sc[nt][r] = v;
                        mnew = fmaxf(mnew, v);
                    }
                }
            } else {
#pragma unroll
                for (int nt = 0; nt < 4; ++nt)
#pragma unroll
                    for (int r = 0; r < 4; ++r) mnew = fmaxf(mnew, sc[nt][r]);
            }
            // cross-quad reduce (q-row spread over lanes l16, +16, +32, +48)
            mnew = fmaxf(mnew, __shfl_xor(mnew, 16));
            mnew = fmaxf(mnew, __shfl_xor(mnew, 32));
            // T13 defer-max: rescale only if some lane's max grew by > 8
            if (!__all(mnew - m_i <= 8.0f)) {
                const float mi = fmaxf(m_i, mnew);
                const float alpha = exp2f(m_i - mi);   // base-2 softmax
                m_i = mi;
                l_i *= alpha;
#pragma unroll
                for (int dt = 0; dt < 8; ++dt)
#pragma unroll
                    for (int r = 0; r < 4; ++r) accO[dt][r] *= alpha;
            }

            float rs = 0.f;
#pragma unroll
            for (int nt = 0; nt < 4; ++nt)
#pragma unroll
                for (int r = 0; r < 4; ++r) {
                    float pv = exp2f(sc[nt][r] - m_i);   // bounded by 2^8
                    sc[nt][r] = pv;
                    rs += pv;
                }
            rs += __shfl_xor(rs, 16);
            rs += __shfl_xor(rs, 32);
            l_i += rs;

            // P^T -> LDS: row q=l16 (64 k's), 8B groups swizzled by g^=swzP
#pragma unroll
            for (int nt = 0; nt < 4; ++nt) {
                bf16x4 pw;
                pw.x = (__bf16)sc[nt][0]; pw.y = (__bf16)sc[nt][1];
                pw.z = (__bf16)sc[nt][2]; pw.w = (__bf16)sc[nt][3];
                int g = (nt * 4 + quad) ^ swzP;
                *(bf16x4*)(Psw + l16 * 64 + g * 4) = pw;
            }
            // O^T += V^T . P^T  (A = Vs rows, B = P^T frags from Psw)
            __builtin_amdgcn_s_setprio(1);
#pragma unroll
            for (int kc = 0; kc < 2; ++kc) {
                int gk = (kc * 8 + quad * 2) ^ swzP;   // even -> 16B aligned
                bf16x8 pb = *(const bf16x8*)(Psw + l16 * 64 + gk * 4);
#pragma unroll
                for (int dt = 0; dt < 8; ++dt) {
                    int vrow = dt * 16 + l16;
                    int vch = (kc * 4 + quad) ^ (vrow & 7);
                    bf16x8 vf = *(const bf16x8*)(Vcur + vrow * 64 + vch * 8);
                    accO[dt] = __builtin_amdgcn_mfma_f32_16x16x32_bf16(vf, pb, accO[dt], 0, 0, 0);
                }
            }
            __builtin_amdgcn_s_setprio(0);
            // no trailing barrier: ring slot (kt+3)&3 written next strip is
            // not read by any wave still inside strips kt or kt+1.
        }

        // ---- epilogue: accO is O^T; lane writes 8x 8B runs of its q-row ----
        const float inv = 1.0f / l_i;
        __bf16* orow = Og + (size_t)(b * T_ + qpos) * D_ + h * DK;
#pragma unroll
        for (int dt = 0; dt < 8; ++dt) {
            bf16x4 ow;
            ow.x = (__bf16)(accO[dt][0] * inv);
            ow.y = (__bf16)(accO[dt][1] * inv);
            ow.z = (__bf16)(accO[dt][2] * inv);
            ow.w = (__bf16)(accO[dt][3] * inv);
            *(bf16x4*)(orow + dt * 16 + quad * 4) = ow;
        }
    }
}

// ---------------------------------------------------------------------------
extern "C" void kernel_launch(void* const* d_in, const int* in_sizes, int n_in,
                              void* d_out, int out_size, void* d_ws, size_t ws_size,
                              hipStream_t stream) {
    const float* x    = (const float*)d_in[0];
    const float* Wkqv = (const float*)d_in[1];
    const float* bkqv = (const float*)d_in[2];
    const float* Wo   = (const float*)d_in[3];
    const float* bo   = (const float*)d_in[4];
    float* out = (float*)d_out;

    // workspace layout (112 MiB used)
    char* p = (char*)d_ws;
    __bf16* xb    = (__bf16*)p; p += (size_t)BT_ * D_ * 2;  // 16 MiB
    __bf16* WkqvT = (__bf16*)p; p += (size_t)D_ * N3 * 2;   // 24 MiB
    __bf16* WoT   = (__bf16*)p; p += (size_t)D_ * D_ * 2;   //  8 MiB
    __bf16* qh    = (__bf16*)p; p += (size_t)BT_ * D_ * 2;  // 16 MiB
    __bf16* kh    = (__bf16*)p; p += (size_t)BT_ * D_ * 2;  // 16 MiB
    __bf16* vT    = (__bf16*)p; p += (size_t)BT_ * D_ * 2;  // 16 MiB
    __bf16* ao    = (__bf16*)p; p += (size_t)BT_ * D_ * 2;  // 16 MiB

    prep_kernel<<<12288, 256, 0, stream>>>(x, xb, Wkqv, WkqvT, Wo, WoT);
    gemm_kqv<<<dim3(N3 / 128, BT_ / 128), 256, 0, stream>>>(xb, WkqvT, bkqv, kh, qh, vT, BT_, N3, D_);
    fa_kernel<<<dim3(B_ * H_, 8), 512, 0, stream>>>(qh, kh, vT, ao);
    gemm_bt<float><<<dim3(D_ / 128, BT_ / 128), 256, 0, stream>>>(ao, WoT, bo, out, BT_, D_, D_);
}